// Round 1
// baseline (527.899 us; speedup 1.0000x reference)
//
#include <hip/hip_runtime.h>
#include <hip/hip_bf16.h>
#include <math.h>

#define NN 50000
#define NE 800000
// node in-dim 128, edge in-dim 16, out 4 heads x 32 = 128

// ---------------- K1: projection GEMM  Y[N,128] = X[N,128] @ W[128,128]^T ----------------
// 256 threads, 64 rows/block, K processed in 2 chunks of 64. W staged transposed in LDS.
__global__ __launch_bounds__(256) void k_proj(const float* __restrict__ X,
                                              const float* __restrict__ W,
                                              float* __restrict__ Y, int n) {
    extern __shared__ char smem[];
    float* Ws = (float*)smem;                 // [64][132] (k-major, padded)
    float* Xs = (float*)(smem + 64 * 132 * 4); // [64][132]

    const int t  = threadIdx.x;
    const int cg = t & 31;          // 32 column-quads -> c0 = cg*4
    const int rg = t >> 5;          // 8 row groups, rows rg + 8j
    const int c0 = cg * 4;
    const int row0 = blockIdx.x * 64;

    float acc[8][4];
#pragma unroll
    for (int j = 0; j < 8; ++j)
#pragma unroll
        for (int i = 0; i < 4; ++i) acc[j][i] = 0.f;

    // stage 64 rows of X (float4, coalesced)
#pragma unroll
    for (int it = 0; it < 8; ++it) {
        int flat = t + it * 256;        // float4 index, 32 per row
        int r = flat >> 5;
        int k4 = (flat & 31) * 4;
        float4 v = make_float4(0.f, 0.f, 0.f, 0.f);
        if (row0 + r < n)
            v = *reinterpret_cast<const float4*>(X + (size_t)(row0 + r) * 128 + k4);
        *reinterpret_cast<float4*>(&Xs[r * 132 + k4]) = v;
    }

    for (int kc = 0; kc < 2; ++kc) {
        const int kbase = kc * 64;
        __syncthreads();   // protect Ws reuse (also covers Xs staging on first pass)
        // stage W chunk transposed: Ws[k][c] = W[c][kbase+k]
#pragma unroll
        for (int it = 0; it < 8; ++it) {
            int flat = t + it * 256;    // 128 c x 16 quads
            int c = flat >> 4;
            int q = flat & 15;
            float4 v = *reinterpret_cast<const float4*>(W + (size_t)c * 128 + kbase + q * 4);
            Ws[(q * 4 + 0) * 132 + c] = v.x;
            Ws[(q * 4 + 1) * 132 + c] = v.y;
            Ws[(q * 4 + 2) * 132 + c] = v.z;
            Ws[(q * 4 + 3) * 132 + c] = v.w;
        }
        __syncthreads();
#pragma unroll
        for (int kq = 0; kq < 16; ++kq) {
            const float4 w0 = *reinterpret_cast<const float4*>(&Ws[(kq * 4 + 0) * 132 + c0]);
            const float4 w1 = *reinterpret_cast<const float4*>(&Ws[(kq * 4 + 1) * 132 + c0]);
            const float4 w2 = *reinterpret_cast<const float4*>(&Ws[(kq * 4 + 2) * 132 + c0]);
            const float4 w3 = *reinterpret_cast<const float4*>(&Ws[(kq * 4 + 3) * 132 + c0]);
#pragma unroll
            for (int j = 0; j < 8; ++j) {
                const float4 xv = *reinterpret_cast<const float4*>(
                    &Xs[(rg + j * 8) * 132 + kbase + kq * 4]);
                acc[j][0] += xv.x * w0.x + xv.y * w1.x + xv.z * w2.x + xv.w * w3.x;
                acc[j][1] += xv.x * w0.y + xv.y * w1.y + xv.z * w2.y + xv.w * w3.y;
                acc[j][2] += xv.x * w0.z + xv.y * w1.z + xv.z * w2.z + xv.w * w3.z;
                acc[j][3] += xv.x * w0.w + xv.y * w1.w + xv.z * w2.w + xv.w * w3.w;
            }
        }
    }
#pragma unroll
    for (int j = 0; j < 8; ++j) {
        int r = row0 + rg + j * 8;
        if (r < n)
            *reinterpret_cast<float4*>(Y + (size_t)r * 128 + c0) =
                make_float4(acc[j][0], acc[j][1], acc[j][2], acc[j][3]);
    }
}

// ---------------- K1b: el/er per (node, head) ----------------
__global__ void k_elr(const float* __restrict__ F, const float* __restrict__ al,
                      const float* __restrict__ ar, float* __restrict__ el,
                      float* __restrict__ er) {
    int t = blockIdx.x * blockDim.x + threadIdx.x;
    if (t >= NN * 4) return;
    int n = t >> 2, h = t & 3;
    const float* f = F + (size_t)n * 128 + h * 32;
    const float* a = al + h * 32;
    const float* b = ar + h * 32;
    float sl = 0.f, sr = 0.f;
#pragma unroll
    for (int i = 0; i < 8; ++i) {
        float4 fv = *reinterpret_cast<const float4*>(f + i * 4);
        float4 av = *reinterpret_cast<const float4*>(a + i * 4);
        float4 bv = *reinterpret_cast<const float4*>(b + i * 4);
        sl += fv.x * av.x + fv.y * av.y + fv.z * av.z + fv.w * av.w;
        sr += fv.x * bv.x + fv.y * bv.y + fv.z * bv.z + fv.w * bv.w;
    }
    el[t] = sl;
    er[t] = sr;
}

// ---------------- K2: per-edge logits + leaky relu + dst histogram ----------------
__global__ void k_edge_logits(const float* __restrict__ FE, const int* __restrict__ src,
                              const int* __restrict__ dst, const float* __restrict__ ae,
                              const float* __restrict__ el, const float* __restrict__ er,
                              float* __restrict__ logits, int* __restrict__ count) {
    int e = blockIdx.x * blockDim.x + threadIdx.x;
    if (e >= NE) return;
    float fe[16];
#pragma unroll
    for (int i = 0; i < 4; ++i) {
        float4 v = *reinterpret_cast<const float4*>(FE + (size_t)e * 16 + i * 4);
        fe[i * 4 + 0] = v.x; fe[i * 4 + 1] = v.y; fe[i * 4 + 2] = v.z; fe[i * 4 + 3] = v.w;
    }
    int s = src[e], d = dst[e];
    float4 elv = *reinterpret_cast<const float4*>(el + (size_t)s * 4);
    float4 erv = *reinterpret_cast<const float4*>(er + (size_t)d * 4);
    float base[4] = {elv.x, elv.y, elv.z, elv.w};
    float basr[4] = {erv.x, erv.y, erv.z, erv.w};
    float o[4];
#pragma unroll
    for (int h = 0; h < 4; ++h) {
        float ee = 0.f;
#pragma unroll
        for (int i = 0; i < 16; ++i) ee += fe[i] * ae[h * 16 + i];
        float v = base[h] + basr[h] + ee;
        o[h] = v > 0.f ? v : 0.2f * v;
    }
    *reinterpret_cast<float4*>(logits + (size_t)e * 4) = make_float4(o[0], o[1], o[2], o[3]);
    atomicAdd(&count[d], 1);
}

// ---------------- K3: exclusive scan of counts -> row_ptr[N+1] (single block) ----------------
__global__ __launch_bounds__(1024) void k_scan(const int* __restrict__ count,
                                               int* __restrict__ row_ptr) {
    __shared__ int buf[1024];
    __shared__ int carry_s;
    int t = threadIdx.x;
    if (t == 0) carry_s = 0;
    __syncthreads();
    for (int base = 0; base < NN; base += 1024) {
        int c0 = carry_s;
        int v = (base + t < NN) ? count[base + t] : 0;
        buf[t] = v;
        __syncthreads();
        for (int off = 1; off < 1024; off <<= 1) {
            int add = (t >= off) ? buf[t - off] : 0;
            __syncthreads();
            buf[t] += add;
            __syncthreads();
        }
        if (base + t < NN) row_ptr[base + t] = c0 + buf[t] - v;   // exclusive
        if (t == 1023) carry_s = c0 + buf[1023];
        __syncthreads();
    }
    if (t == 0) row_ptr[NN] = carry_s;
}

// ---------------- K4: fill edge list (CSR by dst) ----------------
__global__ void k_fill(const int* __restrict__ dst, int* __restrict__ cursor,
                       int* __restrict__ edge_list) {
    int e = blockIdx.x * blockDim.x + threadIdx.x;
    if (e >= NE) return;
    int d = dst[e];
    int pos = atomicAdd(&cursor[d], 1);
    edge_list[pos] = e;
}

// ---------------- K6: per-node softmax + weighted aggregation (1 wave / node) ----------------
__global__ __launch_bounds__(256) void k_aggr(const float* __restrict__ feat,
                                              const int* __restrict__ src,
                                              const float* __restrict__ logits,
                                              const int* __restrict__ row_ptr,
                                              const int* __restrict__ edge_list,
                                              float* __restrict__ out) {
    int wid = threadIdx.x >> 6;
    int lane = threadIdx.x & 63;
    int node = blockIdx.x * 4 + wid;
    if (node >= NN) return;
    int s0 = row_ptr[node], s1 = row_ptr[node + 1];
    float* o = out + (size_t)node * 128;
    if (s1 == s0) { o[lane] = 0.f; o[lane + 64] = 0.f; return; }

    // pass 1a: per-head max over in-edges
    float m0 = -1e30f, m1 = -1e30f, m2 = -1e30f, m3 = -1e30f;
    for (int i = s0 + lane; i < s1; i += 64) {
        int e = edge_list[i];
        float4 lg = *reinterpret_cast<const float4*>(logits + (size_t)e * 4);
        m0 = fmaxf(m0, lg.x); m1 = fmaxf(m1, lg.y);
        m2 = fmaxf(m2, lg.z); m3 = fmaxf(m3, lg.w);
    }
#pragma unroll
    for (int off = 32; off; off >>= 1) {
        m0 = fmaxf(m0, __shfl_xor(m0, off));
        m1 = fmaxf(m1, __shfl_xor(m1, off));
        m2 = fmaxf(m2, __shfl_xor(m2, off));
        m3 = fmaxf(m3, __shfl_xor(m3, off));
    }
    // pass 1b: per-head sum of exp
    float s0f = 0.f, s1f = 0.f, s2f = 0.f, s3f = 0.f;
    for (int i = s0 + lane; i < s1; i += 64) {
        int e = edge_list[i];
        float4 lg = *reinterpret_cast<const float4*>(logits + (size_t)e * 4);
        s0f += __expf(lg.x - m0); s1f += __expf(lg.y - m1);
        s2f += __expf(lg.z - m2); s3f += __expf(lg.w - m3);
    }
#pragma unroll
    for (int off = 32; off; off >>= 1) {
        s0f += __shfl_xor(s0f, off);
        s1f += __shfl_xor(s1f, off);
        s2f += __shfl_xor(s2f, off);
        s3f += __shfl_xor(s3f, off);
    }

    // pass 2: weighted accumulate. lane owns elements lane (head ha) and lane+64 (head ha+2)
    int ha = lane >> 5;
    float ma = ha ? m1 : m0;
    float mb = ha ? m3 : m2;
    float ra = 1.f / (ha ? s1f : s0f);
    float rb = 1.f / (ha ? s3f : s2f);
    float acc0 = 0.f, acc1 = 0.f;
    for (int i = s0; i < s1; ++i) {
        int e = edge_list[i];
        int sv = src[e];
        float la = logits[(size_t)e * 4 + ha];
        float lb = logits[(size_t)e * 4 + 2 + ha];
        float wa = __expf(la - ma) * ra;
        float wb = __expf(lb - mb) * rb;
        acc0 += wa * feat[(size_t)sv * 128 + lane];
        acc1 += wb * feat[(size_t)sv * 128 + 64 + lane];
    }
    o[lane] = acc0;
    o[lane + 64] = acc1;
}

extern "C" void kernel_launch(void* const* d_in, const int* in_sizes, int n_in,
                              void* d_out, int out_size, void* d_ws, size_t ws_size,
                              hipStream_t stream) {
    const float* feats_node = (const float*)d_in[0];
    const float* feats_edge = (const float*)d_in[1];
    const int*   src        = (const int*)d_in[2];
    const int*   dst        = (const int*)d_in[3];
    const float* W          = (const float*)d_in[4];
    const float* al         = (const float*)d_in[5];
    const float* ar         = (const float*)d_in[6];
    const float* ae         = (const float*)d_in[7];
    float* out = (float*)d_out;

    char* ws = (char*)d_ws;
    size_t off = 0;
    float* feat_n = (float*)(ws + off); off += (size_t)NN * 128 * 4;      // 25.6 MB
    float* el     = (float*)(ws + off); off += (size_t)NN * 4 * 4;
    float* er     = (float*)(ws + off); off += (size_t)NN * 4 * 4;
    float* logits = (float*)(ws + off); off += (size_t)NE * 4 * 4;        // 12.8 MB
    int* count    = (int*)(ws + off);   off += (size_t)NN * 4;
    int* row_ptr  = (int*)(ws + off);   off += (size_t)(NN + 16) * 4;
    int* cursor   = (int*)(ws + off);   off += (size_t)NN * 4;
    int* edge_list= (int*)(ws + off);   off += (size_t)NE * 4;

    hipMemsetAsync(count, 0, (size_t)NN * 4, stream);

    k_proj<<<(NN + 63) / 64, 256, 64 * 132 * 4 * 2, stream>>>(feats_node, W, feat_n, NN);
    k_elr<<<(NN * 4 + 255) / 256, 256, 0, stream>>>(feat_n, al, ar, el, er);
    k_edge_logits<<<(NE + 255) / 256, 256, 0, stream>>>(feats_edge, src, dst, ae, el, er,
                                                        logits, count);
    k_scan<<<1, 1024, 0, stream>>>(count, row_ptr);
    hipMemcpyAsync(cursor, row_ptr, (size_t)NN * 4, hipMemcpyDeviceToDevice, stream);
    k_fill<<<(NE + 255) / 256, 256, 0, stream>>>(dst, cursor, edge_list);
    k_aggr<<<(NN + 3) / 4, 256, 0, stream>>>(feat_n, src, logits, row_ptr, edge_list, out);
}

// Round 3
// 361.063 us; speedup vs baseline: 1.4621x; 1.4621x over previous
//
#include <hip/hip_runtime.h>
#include <hip/hip_bf16.h>
#include <math.h>

#define NN 50000
#define NE 800000
#define SCAN_NB ((NN + 255) / 256)          // 196
#define PROJ_ROWS_PER_BLOCK 112             // 7 groups of 16 rows
#define PROJ_NBLK ((NN + PROJ_ROWS_PER_BLOCK - 1) / PROJ_ROWS_PER_BLOCK)  // 447

// ---------------- K1: fused projection + el/er (f32) + bf16 feat ----------------
// LDS: Wc[64][64] float2 pairs (one 64-wide K chunk of (W[c][k],W[c+64][k])) + Xs[16][128]
// Total LDS = 32 KiB + 8 KiB = 40 KiB (safely under 64 KiB).
__global__ __launch_bounds__(256) void k_proj2(
    const float* __restrict__ X, const float* __restrict__ W,
    const float* __restrict__ al, const float* __restrict__ ar,
    __hip_bfloat16* __restrict__ FB, float* __restrict__ el, float* __restrict__ er)
{
    extern __shared__ char smem[];
    float* WtW = (float*)smem;                   // word view of Wc[64][64] float2
    float* Xs  = (float*)(smem + 64 * 64 * 8);   // [16][128]

    const int t = threadIdx.x;
    const int wave = t >> 6, lane = t & 63;

    const float alv0 = al[lane], alv1 = al[lane + 64];
    const float arv0 = ar[lane], arv1 = ar[lane + 64];
    const int rowBase = blockIdx.x * PROJ_ROWS_PER_BLOCK;
    const float2* WtP = (const float2*)WtW;

    for (int g = 0; g < 7; ++g) {
        int r0 = rowBase + g * 16;
        __syncthreads();   // previous group's reads of Xs/WtW complete
        // stage 16 rows of X, coalesced float4
#pragma unroll
        for (int i = 0; i < 2; ++i) {
            int idx = t + i * 256;                 // 512 float4
            int rr = idx >> 5, c4 = (idx & 31) * 4;
            int r = r0 + rr;
            float4 v = make_float4(0.f, 0.f, 0.f, 0.f);
            if (r < NN) v = *reinterpret_cast<const float4*>(X + (size_t)r * 128 + c4);
            *reinterpret_cast<float4*>(&Xs[rr * 128 + c4]) = v;
        }

        float a00 = 0.f, a01 = 0.f, a10 = 0.f, a11 = 0.f;
        float a20 = 0.f, a21 = 0.f, a30 = 0.f, a31 = 0.f;

        for (int kc = 0; kc < 2; ++kc) {
            if (kc) __syncthreads();   // compute of chunk 0 done before overwriting WtW
            // stage W chunk transposed as pairs: word (k)*128 + (c&63)*2 + (c>>6),
            // value = W[c][kc*64 + k], k in 0..63
#pragma unroll
            for (int it = 0; it < 8; ++it) {
                int flat = t + it * 256;        // 2048 float4 loads
                int c = flat & 127, q = flat >> 7;   // q in 0..15
                float4 v = *reinterpret_cast<const float4*>(
                    W + (size_t)c * 128 + kc * 64 + q * 4);
                int base = (c & 63) * 2 + (c >> 6);
                WtW[(q * 4 + 0) * 128 + base] = v.x;
                WtW[(q * 4 + 1) * 128 + base] = v.y;
                WtW[(q * 4 + 2) * 128 + base] = v.z;
                WtW[(q * 4 + 3) * 128 + base] = v.w;
            }
            __syncthreads();

            const float* xr0 = &Xs[(wave * 4 + 0) * 128 + kc * 64];
            const float* xr1 = &Xs[(wave * 4 + 1) * 128 + kc * 64];
            const float* xr2 = &Xs[(wave * 4 + 2) * 128 + kc * 64];
            const float* xr3 = &Xs[(wave * 4 + 3) * 128 + kc * 64];
#pragma unroll 2
            for (int k4 = 0; k4 < 16; ++k4) {
                float2 wa = WtP[(k4 * 4 + 0) * 64 + lane];
                float2 wb = WtP[(k4 * 4 + 1) * 64 + lane];
                float2 wc = WtP[(k4 * 4 + 2) * 64 + lane];
                float2 wd = WtP[(k4 * 4 + 3) * 64 + lane];
                float4 x0 = *reinterpret_cast<const float4*>(&xr0[k4 * 4]);
                float4 x1 = *reinterpret_cast<const float4*>(&xr1[k4 * 4]);
                float4 x2 = *reinterpret_cast<const float4*>(&xr2[k4 * 4]);
                float4 x3 = *reinterpret_cast<const float4*>(&xr3[k4 * 4]);
                a00 += x0.x * wa.x + x0.y * wb.x + x0.z * wc.x + x0.w * wd.x;
                a01 += x0.x * wa.y + x0.y * wb.y + x0.z * wc.y + x0.w * wd.y;
                a10 += x1.x * wa.x + x1.y * wb.x + x1.z * wc.x + x1.w * wd.x;
                a11 += x1.x * wa.y + x1.y * wb.y + x1.z * wc.y + x1.w * wd.y;
                a20 += x2.x * wa.x + x2.y * wb.x + x2.z * wc.x + x2.w * wd.x;
                a21 += x2.x * wa.y + x2.y * wb.y + x2.z * wc.y + x2.w * wd.y;
                a30 += x3.x * wa.x + x3.y * wb.x + x3.z * wc.x + x3.w * wd.x;
                a31 += x3.x * wa.y + x3.y * wb.y + x3.z * wc.y + x3.w * wd.y;
            }
        }

        // epilogue: bf16 feat + full-precision el/er via 32-lane-group reductions
        float ar0[4] = {a00, a10, a20, a30};
        float ar1[4] = {a01, a11, a21, a31};
#pragma unroll
        for (int r = 0; r < 4; ++r) {
            int row = r0 + wave * 4 + r;
            if (row < NN) {
                FB[(size_t)row * 128 + lane]      = __float2bfloat16(ar0[r]);
                FB[(size_t)row * 128 + lane + 64] = __float2bfloat16(ar1[r]);
                float pl = ar0[r] * alv0, pr = ar0[r] * arv0;
                float ql = ar1[r] * alv1, qr = ar1[r] * arv1;
#pragma unroll
                for (int off = 16; off; off >>= 1) {
                    pl += __shfl_xor(pl, off);
                    pr += __shfl_xor(pr, off);
                    ql += __shfl_xor(ql, off);
                    qr += __shfl_xor(qr, off);
                }
                if ((lane & 31) == 0) {
                    int h = lane >> 5;
                    el[row * 4 + h]     = pl;
                    er[row * 4 + h]     = pr;
                    el[row * 4 + 2 + h] = ql;
                    er[row * 4 + 2 + h] = qr;
                }
            }
        }
    }
}

// ---------------- K2: per-edge logits + leaky relu + dst histogram ----------------
__global__ void k_edge_logits(const float* __restrict__ FE, const int* __restrict__ src,
                              const int* __restrict__ dst, const float* __restrict__ ae,
                              const float* __restrict__ el, const float* __restrict__ er,
                              float* __restrict__ logits, int* __restrict__ count) {
    int e = blockIdx.x * blockDim.x + threadIdx.x;
    if (e >= NE) return;
    float fe[16];
#pragma unroll
    for (int i = 0; i < 4; ++i) {
        float4 v = *reinterpret_cast<const float4*>(FE + (size_t)e * 16 + i * 4);
        fe[i * 4 + 0] = v.x; fe[i * 4 + 1] = v.y; fe[i * 4 + 2] = v.z; fe[i * 4 + 3] = v.w;
    }
    int s = src[e], d = dst[e];
    float4 elv = *reinterpret_cast<const float4*>(el + (size_t)s * 4);
    float4 erv = *reinterpret_cast<const float4*>(er + (size_t)d * 4);
    float base[4] = {elv.x, elv.y, elv.z, elv.w};
    float basr[4] = {erv.x, erv.y, erv.z, erv.w};
    float o[4];
#pragma unroll
    for (int h = 0; h < 4; ++h) {
        float ee = 0.f;
#pragma unroll
        for (int i = 0; i < 16; ++i) ee += fe[i] * ae[h * 16 + i];
        float v = base[h] + basr[h] + ee;
        o[h] = v > 0.f ? v : 0.2f * v;
    }
    *reinterpret_cast<float4*>(logits + (size_t)e * 4) = make_float4(o[0], o[1], o[2], o[3]);
    atomicAdd(&count[d], 1);
}

// ---------------- K3: hierarchical scan ----------------
__global__ __launch_bounds__(256) void k_scan_a(const int* __restrict__ count,
                                                int* __restrict__ pre,
                                                int* __restrict__ bsum) {
    __shared__ int buf[256];
    int t = threadIdx.x;
    int gid = blockIdx.x * 256 + t;
    int v = (gid < NN) ? count[gid] : 0;
    int x = v;
    buf[t] = x;
    __syncthreads();
    for (int off = 1; off < 256; off <<= 1) {
        int add = (t >= off) ? buf[t - off] : 0;
        __syncthreads();
        x += add;
        buf[t] = x;
        __syncthreads();
    }
    if (gid < NN) pre[gid] = x - v;       // exclusive within block
    if (t == 255) bsum[blockIdx.x] = x;   // block total
}

__global__ __launch_bounds__(256) void k_scan_b(const int* __restrict__ bsum,
                                                int* __restrict__ bofs) {
    __shared__ int buf[256];
    int t = threadIdx.x;
    int v = (t < SCAN_NB) ? bsum[t] : 0;
    int x = v;
    buf[t] = x;
    __syncthreads();
    for (int off = 1; off < 256; off <<= 1) {
        int add = (t >= off) ? buf[t - off] : 0;
        __syncthreads();
        x += add;
        buf[t] = x;
        __syncthreads();
    }
    if (t < SCAN_NB) bofs[t] = x - v;     // exclusive block offsets
    if (t == 255) bofs[SCAN_NB] = x;      // grand total
}

__global__ __launch_bounds__(256) void k_scan_c(int* __restrict__ pre,
                                                const int* __restrict__ bofs,
                                                int* __restrict__ cursor) {
    int gid = blockIdx.x * 256 + threadIdx.x;
    if (gid < NN) {
        int val = pre[gid] + bofs[gid >> 8];
        pre[gid] = val;        // pre doubles as row_ptr
        cursor[gid] = val;
    }
    if (gid == 0) pre[NN] = bofs[SCAN_NB];
}

// ---------------- K4: fill edge list (CSR by dst) ----------------
__global__ void k_fill(const int* __restrict__ dst, int* __restrict__ cursor,
                       int* __restrict__ edge_list) {
    int e = blockIdx.x * blockDim.x + threadIdx.x;
    if (e >= NE) return;
    int d = dst[e];
    int pos = atomicAdd(&cursor[d], 1);
    edge_list[pos] = e;
}

// ---------------- K6: per-node softmax + weighted aggregation (1 wave / node, bf16 feat) ----
__global__ __launch_bounds__(256) void k_aggr2(const __hip_bfloat16* __restrict__ FB,
                                               const int* __restrict__ src,
                                               const float* __restrict__ logits,
                                               const int* __restrict__ row_ptr,
                                               const int* __restrict__ edge_list,
                                               float* __restrict__ out) {
    int wid = threadIdx.x >> 6;
    int lane = threadIdx.x & 63;
    int node = blockIdx.x * 4 + wid;
    if (node >= NN) return;
    int s0 = row_ptr[node], s1 = row_ptr[node + 1];
    float2* o2 = reinterpret_cast<float2*>(out + (size_t)node * 128);
    if (s1 == s0) { o2[lane] = make_float2(0.f, 0.f); return; }

    // pass 1a: per-head max
    float m0 = -1e30f, m1 = -1e30f, m2 = -1e30f, m3 = -1e30f;
    for (int i = s0 + lane; i < s1; i += 64) {
        int e = edge_list[i];
        float4 lg = *reinterpret_cast<const float4*>(logits + (size_t)e * 4);
        m0 = fmaxf(m0, lg.x); m1 = fmaxf(m1, lg.y);
        m2 = fmaxf(m2, lg.z); m3 = fmaxf(m3, lg.w);
    }
#pragma unroll
    for (int off = 32; off; off >>= 1) {
        m0 = fmaxf(m0, __shfl_xor(m0, off));
        m1 = fmaxf(m1, __shfl_xor(m1, off));
        m2 = fmaxf(m2, __shfl_xor(m2, off));
        m3 = fmaxf(m3, __shfl_xor(m3, off));
    }
    // pass 1b: per-head sum of exp
    float s0f = 0.f, s1f = 0.f, s2f = 0.f, s3f = 0.f;
    for (int i = s0 + lane; i < s1; i += 64) {
        int e = edge_list[i];
        float4 lg = *reinterpret_cast<const float4*>(logits + (size_t)e * 4);
        s0f += __expf(lg.x - m0); s1f += __expf(lg.y - m1);
        s2f += __expf(lg.z - m2); s3f += __expf(lg.w - m3);
    }
#pragma unroll
    for (int off = 32; off; off >>= 1) {
        s0f += __shfl_xor(s0f, off);
        s1f += __shfl_xor(s1f, off);
        s2f += __shfl_xor(s2f, off);
        s3f += __shfl_xor(s3f, off);
    }

    // pass 2: lane owns output elements (2*lane, 2*lane+1), head = lane>>4
    int ha = lane >> 4;
    float mh = (ha == 0) ? m0 : (ha == 1) ? m1 : (ha == 2) ? m2 : m3;
    float sh = (ha == 0) ? s0f : (ha == 1) ? s1f : (ha == 2) ? s2f : s3f;
    float rh = 1.f / sh;
    const unsigned short* FBu = reinterpret_cast<const unsigned short*>(FB);
    float acc0 = 0.f, acc1 = 0.f;
    int i = s0;
    for (; i + 1 < s1; i += 2) {
        int e0 = edge_list[i], e1 = edge_list[i + 1];
        int v0 = src[e0], v1 = src[e1];
        float lg0 = logits[(size_t)e0 * 4 + ha];
        float lg1 = logits[(size_t)e1 * 4 + ha];
        ushort2 f0 = *reinterpret_cast<const ushort2*>(FBu + (size_t)v0 * 128 + 2 * lane);
        ushort2 f1 = *reinterpret_cast<const ushort2*>(FBu + (size_t)v1 * 128 + 2 * lane);
        float w0 = __expf(lg0 - mh) * rh;
        float w1 = __expf(lg1 - mh) * rh;
        acc0 += w0 * __uint_as_float((unsigned)f0.x << 16)
              + w1 * __uint_as_float((unsigned)f1.x << 16);
        acc1 += w0 * __uint_as_float((unsigned)f0.y << 16)
              + w1 * __uint_as_float((unsigned)f1.y << 16);
    }
    if (i < s1) {
        int e0 = edge_list[i];
        int v0 = src[e0];
        float lg0 = logits[(size_t)e0 * 4 + ha];
        ushort2 f0 = *reinterpret_cast<const ushort2*>(FBu + (size_t)v0 * 128 + 2 * lane);
        float w0 = __expf(lg0 - mh) * rh;
        acc0 += w0 * __uint_as_float((unsigned)f0.x << 16);
        acc1 += w0 * __uint_as_float((unsigned)f0.y << 16);
    }
    o2[lane] = make_float2(acc0, acc1);
}

extern "C" void kernel_launch(void* const* d_in, const int* in_sizes, int n_in,
                              void* d_out, int out_size, void* d_ws, size_t ws_size,
                              hipStream_t stream) {
    const float* feats_node = (const float*)d_in[0];
    const float* feats_edge = (const float*)d_in[1];
    const int*   src        = (const int*)d_in[2];
    const int*   dst        = (const int*)d_in[3];
    const float* W          = (const float*)d_in[4];
    const float* al         = (const float*)d_in[5];
    const float* ar         = (const float*)d_in[6];
    const float* ae         = (const float*)d_in[7];
    float* out = (float*)d_out;

    char* ws = (char*)d_ws;
    size_t off = 0;
    __hip_bfloat16* feat_b = (__hip_bfloat16*)(ws + off); off += (size_t)NN * 128 * 2; // 12.8MB
    float* el     = (float*)(ws + off); off += (size_t)NN * 4 * 4;
    float* er     = (float*)(ws + off); off += (size_t)NN * 4 * 4;
    float* logits = (float*)(ws + off); off += (size_t)NE * 4 * 4;                      // 12.8MB
    int* count    = (int*)(ws + off);   off += (size_t)NN * 4;
    int* row_ptr  = (int*)(ws + off);   off += (size_t)(NN + 16) * 4;
    int* cursor   = (int*)(ws + off);   off += (size_t)NN * 4;
    int* bsum     = (int*)(ws + off);   off += (size_t)(SCAN_NB + 16) * 4;
    int* bofs     = (int*)(ws + off);   off += (size_t)(SCAN_NB + 16) * 4;
    int* edge_list= (int*)(ws + off);   off += (size_t)NE * 4;

    hipMemsetAsync(count, 0, (size_t)NN * 4, stream);

    size_t proj_lds = 64 * 64 * 8 + 16 * 128 * 4;   // 40960 B
    k_proj2<<<PROJ_NBLK, 256, proj_lds, stream>>>(feats_node, W, al, ar, feat_b, el, er);
    k_edge_logits<<<(NE + 255) / 256, 256, 0, stream>>>(feats_edge, src, dst, ae, el, er,
                                                        logits, count);
    k_scan_a<<<SCAN_NB, 256, 0, stream>>>(count, row_ptr, bsum);
    k_scan_b<<<1, 256, 0, stream>>>(bsum, bofs);
    k_scan_c<<<SCAN_NB, 256, 0, stream>>>(row_ptr, bofs, cursor);
    k_fill<<<(NE + 255) / 256, 256, 0, stream>>>(dst, cursor, edge_list);
    k_aggr2<<<(NN + 3) / 4, 256, 0, stream>>>(feat_b, src, logits, row_ptr, edge_list, out);
}

// Round 4
// 323.476 us; speedup vs baseline: 1.6320x; 1.1162x over previous
//
#include <hip/hip_runtime.h>
#include <hip/hip_bf16.h>
#include <math.h>

#define NN 50000
#define NE 800000
#define SCAN_NB ((NN + 255) / 256)            // 196
#define PROJ_NBLK 512
#define PROJ_RPB ((NN + PROJ_NBLK - 1) / PROJ_NBLK)   // 98 rows per block

// ---------------- K0: histogram of dst ----------------
__global__ void k_hist(const int* __restrict__ dst, int* __restrict__ count) {
    int e = blockIdx.x * 256 + threadIdx.x;
    if (e < NE) atomicAdd(&count[dst[e]], 1);
}

// ---------------- K1: hierarchical scan ----------------
__global__ __launch_bounds__(256) void k_scan_a(const int* __restrict__ count,
                                                int* __restrict__ pre,
                                                int* __restrict__ bsum) {
    __shared__ int buf[256];
    int t = threadIdx.x;
    int gid = blockIdx.x * 256 + t;
    int v = (gid < NN) ? count[gid] : 0;
    int x = v;
    buf[t] = x;
    __syncthreads();
    for (int off = 1; off < 256; off <<= 1) {
        int add = (t >= off) ? buf[t - off] : 0;
        __syncthreads();
        x += add;
        buf[t] = x;
        __syncthreads();
    }
    if (gid < NN) pre[gid] = x - v;       // exclusive within block
    if (t == 255) bsum[blockIdx.x] = x;   // block total
}

__global__ __launch_bounds__(256) void k_scan_b(const int* __restrict__ bsum,
                                                int* __restrict__ bofs) {
    __shared__ int buf[256];
    int t = threadIdx.x;
    int v = (t < SCAN_NB) ? bsum[t] : 0;
    int x = v;
    buf[t] = x;
    __syncthreads();
    for (int off = 1; off < 256; off <<= 1) {
        int add = (t >= off) ? buf[t - off] : 0;
        __syncthreads();
        x += add;
        buf[t] = x;
        __syncthreads();
    }
    if (t < SCAN_NB) bofs[t] = x - v;     // exclusive block offsets
    if (t == 255) bofs[SCAN_NB] = x;      // grand total
}

__global__ __launch_bounds__(256) void k_scan_c(int* __restrict__ pre,
                                                const int* __restrict__ bofs,
                                                int* __restrict__ cursor) {
    int gid = blockIdx.x * 256 + threadIdx.x;
    if (gid < NN) {
        int val = pre[gid] + bofs[gid >> 8];
        pre[gid] = val;        // pre doubles as row_ptr
        cursor[gid] = val;
    }
    if (gid == 0) pre[NN] = bofs[SCAN_NB];
}

// ---------------- K2: projection with register-resident W + fused el/er ----------------
// wave w owns columns [w*32, w*32+32) == head w; lane l: col c = w*32+(l&31),
// k-half kh = (l>>5)*64. W slice in 16 float4 VGPRs. X rows stream via LDS.
__global__ __launch_bounds__(256) void k_proj3(
    const float* __restrict__ X, const float* __restrict__ W,
    const float* __restrict__ al, const float* __restrict__ ar,
    __hip_bfloat16* __restrict__ FB, float* __restrict__ el, float* __restrict__ er)
{
    __shared__ float Xs[16 * 128];
    const int t = threadIdx.x;
    const int w = t >> 6, l = t & 63;
    const int c = w * 32 + (l & 31);
    const int kh = (l >> 5) * 64;

    float4 wreg[16];
#pragma unroll
    for (int j = 0; j < 16; ++j)
        wreg[j] = *reinterpret_cast<const float4*>(W + (size_t)c * 128 + kh + j * 4);

    const float alv = al[c], arv = ar[c];
    const int rowLo = blockIdx.x * PROJ_RPB;
    const int rowHi = (rowLo + PROJ_RPB < NN) ? rowLo + PROJ_RPB : NN;

    for (int r0 = rowLo; r0 < rowHi; r0 += 16) {
        __syncthreads();
#pragma unroll
        for (int i = 0; i < 2; ++i) {
            int idx = t + i * 256;                 // 512 float4 slots
            int rr = idx >> 5, c4 = (idx & 31) * 4;
            int r = r0 + rr;
            float4 v = make_float4(0.f, 0.f, 0.f, 0.f);
            if (r < NN) v = *reinterpret_cast<const float4*>(X + (size_t)r * 128 + c4);
            *reinterpret_cast<float4*>(&Xs[rr * 128 + c4]) = v;
        }
        __syncthreads();
        int nr = rowHi - r0; if (nr > 16) nr = 16;
        for (int rr = 0; rr < nr; ++rr) {
            const float4* xp = reinterpret_cast<const float4*>(&Xs[rr * 128 + kh]);
            float a0 = 0.f, a1 = 0.f, a2 = 0.f, a3 = 0.f;
#pragma unroll
            for (int j = 0; j < 16; ++j) {
                float4 x = xp[j];
                a0 += x.x * wreg[j].x; a1 += x.y * wreg[j].y;
                a2 += x.z * wreg[j].z; a3 += x.w * wreg[j].w;
            }
            float tot = (a0 + a1) + (a2 + a3);
            tot += __shfl_xor(tot, 32);            // combine k-halves
            int row = r0 + rr;
            if (l < 32) FB[(size_t)row * 128 + c] = __float2bfloat16(tot);
            float pl = tot * alv, pr = tot * arv;
#pragma unroll
            for (int off = 16; off; off >>= 1) {
                pl += __shfl_xor(pl, off);
                pr += __shfl_xor(pr, off);
            }
            if (l == 0) { el[row * 4 + w] = pl; er[row * 4 + w] = pr; }
        }
    }
}

// ---------------- K3: edge logits + leaky relu, written directly in CSR order ----------------
__global__ void k_logits_fill(const float* __restrict__ FE, const int* __restrict__ src,
                              const int* __restrict__ dst, const float* __restrict__ ae,
                              const float* __restrict__ el, const float* __restrict__ er,
                              int* __restrict__ cursor, float4* __restrict__ lsort,
                              int* __restrict__ ssort) {
    int e = blockIdx.x * 256 + threadIdx.x;
    if (e >= NE) return;
    float fe[16];
#pragma unroll
    for (int i = 0; i < 4; ++i) {
        float4 v = *reinterpret_cast<const float4*>(FE + (size_t)e * 16 + i * 4);
        fe[i * 4 + 0] = v.x; fe[i * 4 + 1] = v.y; fe[i * 4 + 2] = v.z; fe[i * 4 + 3] = v.w;
    }
    int s = src[e], d = dst[e];
    float4 elv = *reinterpret_cast<const float4*>(el + (size_t)s * 4);
    float4 erv = *reinterpret_cast<const float4*>(er + (size_t)d * 4);
    float base[4] = {elv.x + erv.x, elv.y + erv.y, elv.z + erv.z, elv.w + erv.w};
    float o[4];
#pragma unroll
    for (int h = 0; h < 4; ++h) {
        float ee = 0.f;
#pragma unroll
        for (int i = 0; i < 16; ++i) ee += fe[i] * ae[h * 16 + i];
        float v = base[h] + ee;
        o[h] = v > 0.f ? v : 0.2f * v;
    }
    int pos = atomicAdd(&cursor[d], 1);
    lsort[pos] = make_float4(o[0], o[1], o[2], o[3]);
    ssort[pos] = s;
}

// ---------------- K4: softmax + aggregation; 1 wave/node, 4 edges in parallel ----------------
__global__ __launch_bounds__(256) void k_aggr3(
    const __hip_bfloat16* __restrict__ FB, const float* __restrict__ lsf,
    const int* __restrict__ ssort, const int* __restrict__ row_ptr,
    float* __restrict__ out)
{
    int wid = threadIdx.x >> 6, lane = threadIdx.x & 63;
    int node = blockIdx.x * 4 + wid;
    if (node >= NN) return;
    int s0 = row_ptr[node], s1 = row_ptr[node + 1];
    int q = lane & 15, p = lane >> 4;
    float4* o4 = reinterpret_cast<float4*>(out + (size_t)node * 128);
    if (s1 == s0) {
        if (p == 0) {
            o4[2 * q]     = make_float4(0.f, 0.f, 0.f, 0.f);
            o4[2 * q + 1] = make_float4(0.f, 0.f, 0.f, 0.f);
        }
        return;
    }
    const float4* lsort = reinterpret_cast<const float4*>(lsf);

    // pass 1: max + expsum (logits read once for deg<=64; coalesced float4)
    bool have = (s0 + lane) < s1;
    float4 my = have ? lsort[s0 + lane] : make_float4(-1e30f, -1e30f, -1e30f, -1e30f);
    float m0 = my.x, m1 = my.y, m2 = my.z, m3 = my.w;
    for (int i = s0 + lane + 64; i < s1; i += 64) {
        float4 lg = lsort[i];
        m0 = fmaxf(m0, lg.x); m1 = fmaxf(m1, lg.y);
        m2 = fmaxf(m2, lg.z); m3 = fmaxf(m3, lg.w);
    }
#pragma unroll
    for (int off = 32; off; off >>= 1) {
        m0 = fmaxf(m0, __shfl_xor(m0, off)); m1 = fmaxf(m1, __shfl_xor(m1, off));
        m2 = fmaxf(m2, __shfl_xor(m2, off)); m3 = fmaxf(m3, __shfl_xor(m3, off));
    }
    float t0 = have ? __expf(my.x - m0) : 0.f;
    float t1 = have ? __expf(my.y - m1) : 0.f;
    float t2 = have ? __expf(my.z - m2) : 0.f;
    float t3 = have ? __expf(my.w - m3) : 0.f;
    for (int i = s0 + lane + 64; i < s1; i += 64) {
        float4 lg = lsort[i];
        t0 += __expf(lg.x - m0); t1 += __expf(lg.y - m1);
        t2 += __expf(lg.z - m2); t3 += __expf(lg.w - m3);
    }
#pragma unroll
    for (int off = 32; off; off >>= 1) {
        t0 += __shfl_xor(t0, off); t1 += __shfl_xor(t1, off);
        t2 += __shfl_xor(t2, off); t3 += __shfl_xor(t3, off);
    }

    // pass 2: lane quarter p handles edge i=it+p; lane q owns elems 8q..8q+7 (head q>>2)
    int ha = q >> 2;
    float mh = (ha == 0) ? m0 : (ha == 1) ? m1 : (ha == 2) ? m2 : m3;
    float sh = (ha == 0) ? t0 : (ha == 1) ? t1 : (ha == 2) ? t2 : t3;
    float rh = 1.f / sh;
    const unsigned short* FBu = reinterpret_cast<const unsigned short*>(FB);
    float c0 = 0.f, c1 = 0.f, c2 = 0.f, c3 = 0.f, c4 = 0.f, c5 = 0.f, c6 = 0.f, c7 = 0.f;
    for (int it = s0; it < s1; it += 4) {
        int i = it + p;
        if (i < s1) {
            int sv = ssort[i];
            float lg = lsf[(size_t)i * 4 + ha];
            float wgt = __expf(lg - mh) * rh;
            uint4 f = *reinterpret_cast<const uint4*>(FBu + (size_t)sv * 128 + q * 8);
            c0 += wgt * __uint_as_float(f.x << 16);
            c1 += wgt * __uint_as_float(f.x & 0xffff0000u);
            c2 += wgt * __uint_as_float(f.y << 16);
            c3 += wgt * __uint_as_float(f.y & 0xffff0000u);
            c4 += wgt * __uint_as_float(f.z << 16);
            c5 += wgt * __uint_as_float(f.z & 0xffff0000u);
            c6 += wgt * __uint_as_float(f.w << 16);
            c7 += wgt * __uint_as_float(f.w & 0xffff0000u);
        }
    }
#pragma unroll
    for (int off = 16; off <= 32; off <<= 1) {
        c0 += __shfl_xor(c0, off); c1 += __shfl_xor(c1, off);
        c2 += __shfl_xor(c2, off); c3 += __shfl_xor(c3, off);
        c4 += __shfl_xor(c4, off); c5 += __shfl_xor(c5, off);
        c6 += __shfl_xor(c6, off); c7 += __shfl_xor(c7, off);
    }
    if (p == 0) {
        o4[2 * q]     = make_float4(c0, c1, c2, c3);
        o4[2 * q + 1] = make_float4(c4, c5, c6, c7);
    }
}

extern "C" void kernel_launch(void* const* d_in, const int* in_sizes, int n_in,
                              void* d_out, int out_size, void* d_ws, size_t ws_size,
                              hipStream_t stream) {
    const float* feats_node = (const float*)d_in[0];
    const float* feats_edge = (const float*)d_in[1];
    const int*   src        = (const int*)d_in[2];
    const int*   dst        = (const int*)d_in[3];
    const float* W          = (const float*)d_in[4];
    const float* al         = (const float*)d_in[5];
    const float* ar         = (const float*)d_in[6];
    const float* ae         = (const float*)d_in[7];
    float* out = (float*)d_out;

    char* ws = (char*)d_ws;
    size_t off = 0;
    __hip_bfloat16* feat_b = (__hip_bfloat16*)(ws + off); off += (size_t)NN * 128 * 2; // 12.8MB
    float* el     = (float*)(ws + off); off += (size_t)NN * 4 * 4;
    float* er     = (float*)(ws + off); off += (size_t)NN * 4 * 4;
    float* lsort  = (float*)(ws + off); off += (size_t)NE * 4 * 4;                      // 12.8MB
    int* ssort    = (int*)(ws + off);   off += (size_t)NE * 4;                          // 3.2MB
    int* count    = (int*)(ws + off);   off += (size_t)NN * 4;
    int* row_ptr  = (int*)(ws + off);   off += (size_t)(NN + 16) * 4;
    int* cursor   = (int*)(ws + off);   off += (size_t)NN * 4;
    int* bsum     = (int*)(ws + off);   off += (size_t)(SCAN_NB + 16) * 4;
    int* bofs     = (int*)(ws + off);   off += (size_t)(SCAN_NB + 16) * 4;

    hipMemsetAsync(count, 0, (size_t)NN * 4, stream);

    k_hist<<<(NE + 255) / 256, 256, 0, stream>>>(dst, count);
    k_scan_a<<<SCAN_NB, 256, 0, stream>>>(count, row_ptr, bsum);
    k_scan_b<<<1, 256, 0, stream>>>(bsum, bofs);
    k_scan_c<<<SCAN_NB, 256, 0, stream>>>(row_ptr, bofs, cursor);
    k_proj3<<<PROJ_NBLK, 256, 0, stream>>>(feats_node, W, al, ar, feat_b, el, er);
    k_logits_fill<<<(NE + 255) / 256, 256, 0, stream>>>(feats_edge, src, dst, ae, el, er,
                                                        cursor, (float4*)lsort, ssort);
    k_aggr3<<<(NN + 3) / 4, 256, 0, stream>>>(feat_b, lsort, ssort, row_ptr, out);
}

// Round 5
// 304.476 us; speedup vs baseline: 1.7338x; 1.0624x over previous
//
#include <hip/hip_runtime.h>
#include <hip/hip_bf16.h>
#include <math.h>

#define NN 50000
#define NE 800000
#define SCAN_NB ((NN + 255) / 256)            // 196
#define PROJ_NBLK ((NN + 31) / 32)            // 1563, 32 rows/block
#define ELR_NBLK ((NN + 31) / 32)             // 1563, 32 nodes/block

// ---------------- K_prep: v[hlr][k] = sum_d W[h*32+d][k] * a_{l|r}[h*32+d] ----------------
__global__ __launch_bounds__(256) void k_prep(const float* __restrict__ W,
                                              const float* __restrict__ al,
                                              const float* __restrict__ ar,
                                              float* __restrict__ vlr) {
    int t = threadIdx.x;
    int hlr = t >> 5;            // 0..7
    int k4 = t & 31;             // float4 index within row of 128
    int h = hlr & 3;
    const float* a = (hlr & 4) ? ar : al;
    float4 acc = make_float4(0.f, 0.f, 0.f, 0.f);
    for (int d = 0; d < 32; ++d) {
        float av = a[h * 32 + d];
        float4 wv = *reinterpret_cast<const float4*>(W + (size_t)(h * 32 + d) * 128 + k4 * 4);
        acc.x += av * wv.x; acc.y += av * wv.y;
        acc.z += av * wv.z; acc.w += av * wv.w;
    }
    *reinterpret_cast<float4*>(vlr + hlr * 128 + k4 * 4) = acc;
}

// ---------------- K_elr: elr[n][8] = X[n] . v[hlr], 8 lanes per node ----------------
__global__ __launch_bounds__(256) void k_elr(const float* __restrict__ X,
                                             const float* __restrict__ vlr,
                                             float* __restrict__ elr) {
    __shared__ float vs[8 * 128];
    int t = threadIdx.x;
    for (int i = t; i < 1024; i += 256) vs[i] = vlr[i];
    __syncthreads();
    int lane = t & 63, wave = t >> 6;
    int grp = lane >> 3;          // node within wave's 8
    int j = lane & 7;             // k-chunk of 16
    int node = blockIdx.x * 32 + wave * 8 + grp;
    float a0 = 0.f, a1 = 0.f, a2 = 0.f, a3 = 0.f, a4 = 0.f, a5 = 0.f, a6 = 0.f, a7 = 0.f;
    if (node < NN) {
        const float4* xp = reinterpret_cast<const float4*>(X + (size_t)node * 128 + j * 16);
#pragma unroll
        for (int s = 0; s < 4; ++s) {
            float4 xv = xp[s];
            const float* vb = &vs[j * 16 + s * 4];
            float4 v0 = *reinterpret_cast<const float4*>(vb + 0 * 128);
            float4 v1 = *reinterpret_cast<const float4*>(vb + 1 * 128);
            float4 v2 = *reinterpret_cast<const float4*>(vb + 2 * 128);
            float4 v3 = *reinterpret_cast<const float4*>(vb + 3 * 128);
            float4 v4 = *reinterpret_cast<const float4*>(vb + 4 * 128);
            float4 v5 = *reinterpret_cast<const float4*>(vb + 5 * 128);
            float4 v6 = *reinterpret_cast<const float4*>(vb + 6 * 128);
            float4 v7 = *reinterpret_cast<const float4*>(vb + 7 * 128);
            a0 += xv.x * v0.x + xv.y * v0.y + xv.z * v0.z + xv.w * v0.w;
            a1 += xv.x * v1.x + xv.y * v1.y + xv.z * v1.z + xv.w * v1.w;
            a2 += xv.x * v2.x + xv.y * v2.y + xv.z * v2.z + xv.w * v2.w;
            a3 += xv.x * v3.x + xv.y * v3.y + xv.z * v3.z + xv.w * v3.w;
            a4 += xv.x * v4.x + xv.y * v4.y + xv.z * v4.z + xv.w * v4.w;
            a5 += xv.x * v5.x + xv.y * v5.y + xv.z * v5.z + xv.w * v5.w;
            a6 += xv.x * v6.x + xv.y * v6.y + xv.z * v6.z + xv.w * v6.w;
            a7 += xv.x * v7.x + xv.y * v7.y + xv.z * v7.z + xv.w * v7.w;
        }
    }
#pragma unroll
    for (int off = 1; off <= 4; off <<= 1) {
        a0 += __shfl_xor(a0, off); a1 += __shfl_xor(a1, off);
        a2 += __shfl_xor(a2, off); a3 += __shfl_xor(a3, off);
        a4 += __shfl_xor(a4, off); a5 += __shfl_xor(a5, off);
        a6 += __shfl_xor(a6, off); a7 += __shfl_xor(a7, off);
    }
    float outv = (j == 0) ? a0 : (j == 1) ? a1 : (j == 2) ? a2 : (j == 3) ? a3
               : (j == 4) ? a4 : (j == 5) ? a5 : (j == 6) ? a6 : a7;
    if (node < NN) elr[(size_t)node * 8 + j] = outv;
}

// ---------------- K_proj4: pure GEMM -> bf16 feat; W slice in registers ----------------
__global__ __launch_bounds__(256) void k_proj4(const float* __restrict__ X,
                                               const float* __restrict__ W,
                                               __hip_bfloat16* __restrict__ FB) {
    __shared__ float Xs[32 * 128];   // 16 KiB
    const int t = threadIdx.x;
    const int w = t >> 6, l = t & 63;
    const int c = w * 32 + (l & 31);
    const int kh = (l >> 5) * 64;

    float4 wreg[16];
#pragma unroll
    for (int j = 0; j < 16; ++j)
        wreg[j] = *reinterpret_cast<const float4*>(W + (size_t)c * 128 + kh + j * 4);

    const int r0 = blockIdx.x * 32;
#pragma unroll
    for (int i = 0; i < 4; ++i) {
        int idx = t + i * 256;                 // 1024 float4 slots
        int rr = idx >> 5, c4 = (idx & 31) * 4;
        int r = r0 + rr;
        float4 v = make_float4(0.f, 0.f, 0.f, 0.f);
        if (r < NN) v = *reinterpret_cast<const float4*>(X + (size_t)r * 128 + c4);
        *reinterpret_cast<float4*>(&Xs[rr * 128 + c4]) = v;
    }
    __syncthreads();

#pragma unroll 2
    for (int rr = 0; rr < 32; ++rr) {
        const float4* xp = reinterpret_cast<const float4*>(&Xs[rr * 128 + kh]);
        float a0 = 0.f, a1 = 0.f, a2 = 0.f, a3 = 0.f;
#pragma unroll
        for (int j = 0; j < 16; ++j) {
            float4 x = xp[j];
            a0 += x.x * wreg[j].x; a1 += x.y * wreg[j].y;
            a2 += x.z * wreg[j].z; a3 += x.w * wreg[j].w;
        }
        float tot = (a0 + a1) + (a2 + a3);
        tot += __shfl_xor(tot, 32);
        int row = r0 + rr;
        if (l < 32 && row < NN) FB[(size_t)row * 128 + c] = __float2bfloat16(tot);
    }
}

// ---------------- K0: histogram of dst ----------------
__global__ void k_hist(const int* __restrict__ dst, int* __restrict__ count) {
    int e = blockIdx.x * 256 + threadIdx.x;
    if (e < NE) atomicAdd(&count[dst[e]], 1);
}

// ---------------- K1: hierarchical scan ----------------
__global__ __launch_bounds__(256) void k_scan_a(const int* __restrict__ count,
                                                int* __restrict__ pre,
                                                int* __restrict__ bsum) {
    __shared__ int buf[256];
    int t = threadIdx.x;
    int gid = blockIdx.x * 256 + t;
    int v = (gid < NN) ? count[gid] : 0;
    int x = v;
    buf[t] = x;
    __syncthreads();
    for (int off = 1; off < 256; off <<= 1) {
        int add = (t >= off) ? buf[t - off] : 0;
        __syncthreads();
        x += add;
        buf[t] = x;
        __syncthreads();
    }
    if (gid < NN) pre[gid] = x - v;
    if (t == 255) bsum[blockIdx.x] = x;
}

__global__ __launch_bounds__(256) void k_scan_b(const int* __restrict__ bsum,
                                                int* __restrict__ bofs) {
    __shared__ int buf[256];
    int t = threadIdx.x;
    int v = (t < SCAN_NB) ? bsum[t] : 0;
    int x = v;
    buf[t] = x;
    __syncthreads();
    for (int off = 1; off < 256; off <<= 1) {
        int add = (t >= off) ? buf[t - off] : 0;
        __syncthreads();
        x += add;
        buf[t] = x;
        __syncthreads();
    }
    if (t < SCAN_NB) bofs[t] = x - v;
    if (t == 255) bofs[SCAN_NB] = x;
}

__global__ __launch_bounds__(256) void k_scan_c(int* __restrict__ pre,
                                                const int* __restrict__ bofs,
                                                int* __restrict__ cursor) {
    int gid = blockIdx.x * 256 + threadIdx.x;
    if (gid < NN) {
        int val = pre[gid] + bofs[gid >> 8];
        pre[gid] = val;
        cursor[gid] = val;
    }
    if (gid == 0) pre[NN] = bofs[SCAN_NB];
}

// ---------------- K3: edge logits + leaky relu, written in CSR order ----------------
__global__ void k_logits_fill(const float* __restrict__ FE, const int* __restrict__ src,
                              const int* __restrict__ dst, const float* __restrict__ ae,
                              const float* __restrict__ elr, int* __restrict__ cursor,
                              float4* __restrict__ lsort, int* __restrict__ ssort) {
    int e = blockIdx.x * 256 + threadIdx.x;
    if (e >= NE) return;
    float fe[16];
#pragma unroll
    for (int i = 0; i < 4; ++i) {
        float4 v = *reinterpret_cast<const float4*>(FE + (size_t)e * 16 + i * 4);
        fe[i * 4 + 0] = v.x; fe[i * 4 + 1] = v.y; fe[i * 4 + 2] = v.z; fe[i * 4 + 3] = v.w;
    }
    int s = src[e], d = dst[e];
    float4 elv = *reinterpret_cast<const float4*>(elr + (size_t)s * 8);
    float4 erv = *reinterpret_cast<const float4*>(elr + (size_t)d * 8 + 4);
    float base[4] = {elv.x + erv.x, elv.y + erv.y, elv.z + erv.z, elv.w + erv.w};
    float o[4];
#pragma unroll
    for (int h = 0; h < 4; ++h) {
        float ee = 0.f;
#pragma unroll
        for (int i = 0; i < 16; ++i) ee += fe[i] * ae[h * 16 + i];
        float v = base[h] + ee;
        o[h] = v > 0.f ? v : 0.2f * v;
    }
    int pos = atomicAdd(&cursor[d], 1);
    lsort[pos] = make_float4(o[0], o[1], o[2], o[3]);
    ssort[pos] = s;
}

// ---------------- K4: softmax + aggregation; LDS-cached weights, 2x-unrolled gather ----
__global__ __launch_bounds__(256) void k_aggr4(
    const __hip_bfloat16* __restrict__ FB, const float* __restrict__ lsf,
    const int* __restrict__ ssort, const int* __restrict__ row_ptr,
    float* __restrict__ out)
{
    __shared__ float wex[4][64 * 4];     // per-wave exp cache (deg<=64 fast path)
    int wid = threadIdx.x >> 6, lane = threadIdx.x & 63;
    int node = blockIdx.x * 4 + wid;
    if (node >= NN) return;
    int s0 = row_ptr[node], s1 = row_ptr[node + 1];
    int q = lane & 15, p = lane >> 4;
    float4* o4 = reinterpret_cast<float4*>(out + (size_t)node * 128);
    if (s1 == s0) {
        if (p == 0) {
            o4[2 * q]     = make_float4(0.f, 0.f, 0.f, 0.f);
            o4[2 * q + 1] = make_float4(0.f, 0.f, 0.f, 0.f);
        }
        return;
    }
    const float4* lsort = reinterpret_cast<const float4*>(lsf);
    const int deg = s1 - s0;
    const bool small = deg <= 64;

    // pass 1: max + expsum
    bool have = (s0 + lane) < s1;
    float4 my = have ? lsort[s0 + lane] : make_float4(-1e30f, -1e30f, -1e30f, -1e30f);
    float m0 = my.x, m1 = my.y, m2 = my.z, m3 = my.w;
    for (int i = s0 + lane + 64; i < s1; i += 64) {
        float4 lg = lsort[i];
        m0 = fmaxf(m0, lg.x); m1 = fmaxf(m1, lg.y);
        m2 = fmaxf(m2, lg.z); m3 = fmaxf(m3, lg.w);
    }
#pragma unroll
    for (int off = 32; off; off >>= 1) {
        m0 = fmaxf(m0, __shfl_xor(m0, off)); m1 = fmaxf(m1, __shfl_xor(m1, off));
        m2 = fmaxf(m2, __shfl_xor(m2, off)); m3 = fmaxf(m3, __shfl_xor(m3, off));
    }
    float t0 = have ? __expf(my.x - m0) : 0.f;
    float t1 = have ? __expf(my.y - m1) : 0.f;
    float t2 = have ? __expf(my.z - m2) : 0.f;
    float t3 = have ? __expf(my.w - m3) : 0.f;
    if (small && have)
        *reinterpret_cast<float4*>(&wex[wid][lane * 4]) = make_float4(t0, t1, t2, t3);
    float u0 = t0, u1 = t1, u2 = t2, u3 = t3;
    for (int i = s0 + lane + 64; i < s1; i += 64) {
        float4 lg = lsort[i];
        u0 += __expf(lg.x - m0); u1 += __expf(lg.y - m1);
        u2 += __expf(lg.z - m2); u3 += __expf(lg.w - m3);
    }
#pragma unroll
    for (int off = 32; off; off >>= 1) {
        u0 += __shfl_xor(u0, off); u1 += __shfl_xor(u1, off);
        u2 += __shfl_xor(u2, off); u3 += __shfl_xor(u3, off);
    }

    // pass 2: lane quarter p -> edge i=it+p; lane q owns elems 8q..8q+7 (head q>>2)
    int ha = q >> 2;
    float mh = (ha == 0) ? m0 : (ha == 1) ? m1 : (ha == 2) ? m2 : m3;
    float sh = (ha == 0) ? u0 : (ha == 1) ? u1 : (ha == 2) ? u2 : u3;
    float rh = 1.f / sh;
    const unsigned short* FBu = reinterpret_cast<const unsigned short*>(FB);
    float c0 = 0.f, c1 = 0.f, c2 = 0.f, c3 = 0.f, c4 = 0.f, c5 = 0.f, c6 = 0.f, c7 = 0.f;
    if (small) {
        asm volatile("s_waitcnt lgkmcnt(0)" ::: "memory");   // wex visible within wave
        for (int it = s0; it < s1; it += 8) {
            int i0 = it + p, i1 = it + 4 + p;
            bool b0 = i0 < s1, b1 = i1 < s1;
            int sv0 = b0 ? ssort[i0] : 0;
            int sv1 = b1 ? ssort[i1] : 0;
            uint4 f0 = b0 ? *reinterpret_cast<const uint4*>(FBu + (size_t)sv0 * 128 + q * 8)
                          : make_uint4(0, 0, 0, 0);
            uint4 f1 = b1 ? *reinterpret_cast<const uint4*>(FBu + (size_t)sv1 * 128 + q * 8)
                          : make_uint4(0, 0, 0, 0);
            float w0 = b0 ? wex[wid][(i0 - s0) * 4 + ha] * rh : 0.f;
            float w1 = b1 ? wex[wid][(i1 - s0) * 4 + ha] * rh : 0.f;
            c0 += w0 * __uint_as_float(f0.x << 16) + w1 * __uint_as_float(f1.x << 16);
            c1 += w0 * __uint_as_float(f0.x & 0xffff0000u) + w1 * __uint_as_float(f1.x & 0xffff0000u);
            c2 += w0 * __uint_as_float(f0.y << 16) + w1 * __uint_as_float(f1.y << 16);
            c3 += w0 * __uint_as_float(f0.y & 0xffff0000u) + w1 * __uint_as_float(f1.y & 0xffff0000u);
            c4 += w0 * __uint_as_float(f0.z << 16) + w1 * __uint_as_float(f1.z << 16);
            c5 += w0 * __uint_as_float(f0.z & 0xffff0000u) + w1 * __uint_as_float(f1.z & 0xffff0000u);
            c6 += w0 * __uint_as_float(f0.w << 16) + w1 * __uint_as_float(f1.w << 16);
            c7 += w0 * __uint_as_float(f0.w & 0xffff0000u) + w1 * __uint_as_float(f1.w & 0xffff0000u);
        }
    } else {
        for (int it = s0; it < s1; it += 4) {
            int i = it + p;
            if (i < s1) {
                int sv = ssort[i];
                float lg = lsf[(size_t)i * 4 + ha];
                float wgt = __expf(lg - mh) * rh;
                uint4 f = *reinterpret_cast<const uint4*>(FBu + (size_t)sv * 128 + q * 8);
                c0 += wgt * __uint_as_float(f.x << 16);
                c1 += wgt * __uint_as_float(f.x & 0xffff0000u);
                c2 += wgt * __uint_as_float(f.y << 16);
                c3 += wgt * __uint_as_float(f.y & 0xffff0000u);
                c4 += wgt * __uint_as_float(f.z << 16);
                c5 += wgt * __uint_as_float(f.z & 0xffff0000u);
                c6 += wgt * __uint_as_float(f.w << 16);
                c7 += wgt * __uint_as_float(f.w & 0xffff0000u);
            }
        }
    }
#pragma unroll
    for (int off = 16; off <= 32; off <<= 1) {
        c0 += __shfl_xor(c0, off); c1 += __shfl_xor(c1, off);
        c2 += __shfl_xor(c2, off); c3 += __shfl_xor(c3, off);
        c4 += __shfl_xor(c4, off); c5 += __shfl_xor(c5, off);
        c6 += __shfl_xor(c6, off); c7 += __shfl_xor(c7, off);
    }
    if (p == 0) {
        o4[2 * q]     = make_float4(c0, c1, c2, c3);
        o4[2 * q + 1] = make_float4(c4, c5, c6, c7);
    }
}

extern "C" void kernel_launch(void* const* d_in, const int* in_sizes, int n_in,
                              void* d_out, int out_size, void* d_ws, size_t ws_size,
                              hipStream_t stream) {
    const float* feats_node = (const float*)d_in[0];
    const float* feats_edge = (const float*)d_in[1];
    const int*   src        = (const int*)d_in[2];
    const int*   dst        = (const int*)d_in[3];
    const float* W          = (const float*)d_in[4];
    const float* al         = (const float*)d_in[5];
    const float* ar         = (const float*)d_in[6];
    const float* ae         = (const float*)d_in[7];
    float* out = (float*)d_out;

    char* ws = (char*)d_ws;
    size_t off = 0;
    __hip_bfloat16* feat_b = (__hip_bfloat16*)(ws + off); off += (size_t)NN * 128 * 2; // 12.8MB
    float* elr    = (float*)(ws + off); off += (size_t)NN * 8 * 4;                      // 1.6MB
    float* vlr    = (float*)(ws + off); off += (size_t)8 * 128 * 4;
    float* lsort  = (float*)(ws + off); off += (size_t)NE * 4 * 4;                      // 12.8MB
    int* ssort    = (int*)(ws + off);   off += (size_t)NE * 4;                          // 3.2MB
    int* count    = (int*)(ws + off);   off += (size_t)NN * 4;
    int* row_ptr  = (int*)(ws + off);   off += (size_t)(NN + 16) * 4;
    int* cursor   = (int*)(ws + off);   off += (size_t)NN * 4;
    int* bsum     = (int*)(ws + off);   off += (size_t)(SCAN_NB + 16) * 4;
    int* bofs     = (int*)(ws + off);   off += (size_t)(SCAN_NB + 16) * 4;

    hipMemsetAsync(count, 0, (size_t)NN * 4, stream);

    k_hist<<<(NE + 255) / 256, 256, 0, stream>>>(dst, count);
    k_scan_a<<<SCAN_NB, 256, 0, stream>>>(count, row_ptr, bsum);
    k_scan_b<<<1, 256, 0, stream>>>(bsum, bofs);
    k_scan_c<<<SCAN_NB, 256, 0, stream>>>(row_ptr, bofs, cursor);
    k_prep<<<1, 256, 0, stream>>>(W, al, ar, vlr);
    k_elr<<<ELR_NBLK, 256, 0, stream>>>(feats_node, vlr, elr);
    k_proj4<<<PROJ_NBLK, 256, 0, stream>>>(feats_node, W, feat_b);
    k_logits_fill<<<(NE + 255) / 256, 256, 0, stream>>>(feats_edge, src, dst, ae, elr,
                                                        cursor, (float4*)lsort, ssort);
    k_aggr4<<<(NN + 3) / 4, 256, 0, stream>>>(feat_b, lsort, ssort, row_ptr, out);
}